// Round 4
// baseline (789.979 us; speedup 1.0000x reference)
//
#include <hip/hip_runtime.h>
#include <hip/hip_fp16.h>

// Problem constants: B=16, S=512, HID=512, NH=8, DK=64, TH=32, TE=16, scale=1/8

typedef __attribute__((ext_vector_type(8))) __bf16 bf16x8;
typedef __attribute__((ext_vector_type(8))) _Float16 f16x8;
typedef __attribute__((ext_vector_type(4))) float f32x4;

static __device__ __forceinline__ unsigned short f2bf(float f) {
  unsigned u = __float_as_uint(f);
  unsigned r = (u + 0x7fffu + ((u >> 16) & 1u)) >> 16;   // RNE
  return (unsigned short)r;
}
static __device__ __forceinline__ unsigned short f2h(float f) {
  _Float16 h = (_Float16)f;
  return __builtin_bit_cast(unsigned short, h);
}
static __device__ __forceinline__ float h2f(unsigned short u) {
  _Float16 h = __builtin_bit_cast(_Float16, u);
  return (float)h;
}

// ---------------------------------------------------------------------------
// fp32 -> bf16 convert for GEMM inputs: q,k,v and Wq,Wk,Wv,Wo.
// ---------------------------------------------------------------------------
__global__ __launch_bounds__(256) void convert_bf16(
    const float* __restrict__ q, const float* __restrict__ k,
    const float* __restrict__ v, const float* __restrict__ Wq,
    const float* __restrict__ Wk, const float* __restrict__ Wv,
    const float* __restrict__ Wo,
    unsigned short* __restrict__ qb, unsigned short* __restrict__ kb,
    unsigned short* __restrict__ vb, unsigned short* __restrict__ wqb,
    unsigned short* __restrict__ wkb, unsigned short* __restrict__ wvb,
    unsigned short* __restrict__ wob)
{
  const int bid = blockIdx.x;
  const float* src; unsigned short* dst; long blk;
  if (bid < 4096)        { src = q;  dst = qb; blk = bid; }
  else if (bid < 8192)   { src = k;  dst = kb; blk = bid - 4096; }
  else if (bid < 12288)  { src = v;  dst = vb; blk = bid - 8192; }
  else {
    int r = bid - 12288; int w = r >> 8; blk = r & 255;
    src = (w == 0) ? Wq : (w == 1) ? Wk : (w == 2) ? Wv : Wo;
    dst = (w == 0) ? wqb : (w == 1) ? wkb : (w == 2) ? wvb : wob;
  }
  size_t base = (size_t)blk * 1024 + threadIdx.x * 4;
  float4 f = *reinterpret_cast<const float4*>(&src[base]);
  ushort4 o; o.x = f2bf(f.x); o.y = f2bf(f.y); o.z = f2bf(f.z); o.w = f2bf(f.w);
  *reinterpret_cast<ushort4*>(&dst[base]) = o;
}

// ---------------------------------------------------------------------------
// Pack dist|edge<<8 into uint16 (dist<32, edge<16). 2048 blocks x 256 thr x 8.
// ---------------------------------------------------------------------------
__global__ __launch_bounds__(256) void pack_de(
    const int* __restrict__ dist, const int* __restrict__ edge,
    unsigned short* __restrict__ de16)
{
  size_t base = ((size_t)blockIdx.x * 256 + threadIdx.x) * 8;
  int4 d0 = *reinterpret_cast<const int4*>(&dist[base]);
  int4 d1 = *reinterpret_cast<const int4*>(&dist[base + 4]);
  int4 e0 = *reinterpret_cast<const int4*>(&edge[base]);
  int4 e1 = *reinterpret_cast<const int4*>(&edge[base + 4]);
  ushort4 u0, u1;
  u0.x = (unsigned short)(d0.x | (e0.x << 8));
  u0.y = (unsigned short)(d0.y | (e0.y << 8));
  u0.z = (unsigned short)(d0.z | (e0.z << 8));
  u0.w = (unsigned short)(d0.w | (e0.w << 8));
  u1.x = (unsigned short)(d1.x | (e1.x << 8));
  u1.y = (unsigned short)(d1.y | (e1.y << 8));
  u1.z = (unsigned short)(d1.z | (e1.z << 8));
  u1.w = (unsigned short)(d1.w | (e1.w << 8));
  *reinterpret_cast<ushort4*>(&de16[base]) = u0;
  *reinterpret_cast<ushort4*>(&de16[base + 4]) = u1;
}

// ---------------------------------------------------------------------------
// bf16 MFMA GEMM (Q/K proj): Y = f16 head-major [B,H,S,64].
// ---------------------------------------------------------------------------
__global__ __launch_bounds__(256) void proj_qk(
    const unsigned short* __restrict__ X, const unsigned short* __restrict__ W,
    const float* __restrict__ bias, unsigned short* __restrict__ Y)
{
  __shared__ unsigned short As[128][40];
  __shared__ unsigned short Bs[128][40];
  const int tid = threadIdx.x;
  const int m0 = blockIdx.x * 128;
  const int n0 = blockIdx.y * 128;
  const int lane = tid & 63;
  const int w = tid >> 6;
  const int wr = w >> 1, wc = w & 1;
  const int l15 = lane & 15, quad = lane >> 4;

  const int srow = tid & 127;
  const unsigned short* srcrow = (tid < 128) ? &X[(size_t)(m0 + srow) * 512]
                                             : &W[(size_t)(n0 + srow) * 512];
  unsigned short* dstrow = (tid < 128) ? As[srow] : Bs[srow];

  f32x4 acc[4][4];
  #pragma unroll
  for (int i = 0; i < 4; i++)
    #pragma unroll
    for (int j = 0; j < 4; j++) acc[i][j] = (f32x4){0.f, 0.f, 0.f, 0.f};

  for (int k0 = 0; k0 < 512; k0 += 32) {
    #pragma unroll
    for (int u = 0; u < 4; u++) {
      uint4 t4 = *reinterpret_cast<const uint4*>(&srcrow[k0 + u * 8]);
      *reinterpret_cast<uint4*>(&dstrow[u * 8]) = t4;
    }
    __syncthreads();
    bf16x8 af[4], bfr[4];
    #pragma unroll
    for (int mt = 0; mt < 4; mt++)
      af[mt] = *reinterpret_cast<const bf16x8*>(&As[wr * 64 + mt * 16 + l15][quad * 8]);
    #pragma unroll
    for (int nt = 0; nt < 4; nt++)
      bfr[nt] = *reinterpret_cast<const bf16x8*>(&Bs[wc * 64 + nt * 16 + l15][quad * 8]);
    #pragma unroll
    for (int mt = 0; mt < 4; mt++)
      #pragma unroll
      for (int nt = 0; nt < 4; nt++)
        acc[mt][nt] = __builtin_amdgcn_mfma_f32_16x16x32_bf16(
            af[mt], bfr[nt], acc[mt][nt], 0, 0, 0);
    __syncthreads();
  }

  float bn[4];
  #pragma unroll
  for (int nt = 0; nt < 4; nt++)
    bn[nt] = bias[n0 + wc * 64 + nt * 16 + l15];
  #pragma unroll
  for (int mt = 0; mt < 4; mt++) {
    #pragma unroll
    for (int r = 0; r < 4; r++) {
      int m = m0 + wr * 64 + mt * 16 + quad * 4 + r;
      int bb = m >> 9, s = m & 511;
      #pragma unroll
      for (int nt = 0; nt < 4; nt++) {
        int n = n0 + wc * 64 + nt * 16 + l15;
        int h = n >> 6, d = n & 63;
        Y[(((size_t)(bb * 8 + h) * 512) + s) * 64 + d] = f2h(acc[mt][nt][r] + bn[nt]);
      }
    }
  }
}

// ---------------------------------------------------------------------------
// V proj: writes f16 TRANSPOSED+TILED vht[bh][16 chunk][64 d][32 jj].
// ---------------------------------------------------------------------------
__global__ __launch_bounds__(256) void proj_v(
    const unsigned short* __restrict__ X, const unsigned short* __restrict__ W,
    const float* __restrict__ bias, unsigned short* __restrict__ Y)
{
  __shared__ unsigned short As[128][40];
  __shared__ unsigned short Bs[128][40];
  const int tid = threadIdx.x;
  const int m0 = blockIdx.x * 128;
  const int n0 = blockIdx.y * 128;
  const int lane = tid & 63;
  const int w = tid >> 6;
  const int wr = w >> 1, wc = w & 1;
  const int l15 = lane & 15, quad = lane >> 4;

  const int srow = tid & 127;
  const unsigned short* srcrow = (tid < 128) ? &X[(size_t)(m0 + srow) * 512]
                                             : &W[(size_t)(n0 + srow) * 512];
  unsigned short* dstrow = (tid < 128) ? As[srow] : Bs[srow];

  f32x4 acc[4][4];
  #pragma unroll
  for (int i = 0; i < 4; i++)
    #pragma unroll
    for (int j = 0; j < 4; j++) acc[i][j] = (f32x4){0.f, 0.f, 0.f, 0.f};

  for (int k0 = 0; k0 < 512; k0 += 32) {
    #pragma unroll
    for (int u = 0; u < 4; u++) {
      uint4 t4 = *reinterpret_cast<const uint4*>(&srcrow[k0 + u * 8]);
      *reinterpret_cast<uint4*>(&dstrow[u * 8]) = t4;
    }
    __syncthreads();
    bf16x8 af[4], bfr[4];
    #pragma unroll
    for (int mt = 0; mt < 4; mt++)
      af[mt] = *reinterpret_cast<const bf16x8*>(&As[wr * 64 + mt * 16 + l15][quad * 8]);
    #pragma unroll
    for (int nt = 0; nt < 4; nt++)
      bfr[nt] = *reinterpret_cast<const bf16x8*>(&Bs[wc * 64 + nt * 16 + l15][quad * 8]);
    #pragma unroll
    for (int mt = 0; mt < 4; mt++)
      #pragma unroll
      for (int nt = 0; nt < 4; nt++)
        acc[mt][nt] = __builtin_amdgcn_mfma_f32_16x16x32_bf16(
            af[mt], bfr[nt], acc[mt][nt], 0, 0, 0);
    __syncthreads();
  }

  float bn[4];
  #pragma unroll
  for (int nt = 0; nt < 4; nt++)
    bn[nt] = bias[n0 + wc * 64 + nt * 16 + l15];
  #pragma unroll
  for (int mt = 0; mt < 4; mt++) {
    #pragma unroll
    for (int r = 0; r < 4; r++) {
      int m = m0 + wr * 64 + mt * 16 + quad * 4 + r;
      int bb = m >> 9, s = m & 511;
      #pragma unroll
      for (int nt = 0; nt < 4; nt++) {
        int n = n0 + wc * 64 + nt * 16 + l15;
        int h = n >> 6, d = n & 63;
        size_t bh = (size_t)(bb * 8 + h);
        Y[(bh * 16 + (s >> 5)) * 2048 + d * 32 + (s & 31)] = f2h(acc[mt][nt][r] + bn[nt]);
      }
    }
  }
}

// ---------------------------------------------------------------------------
// Bias tables (f16 q/k inputs), block = (bh, quarter of rows). 512 blocks.
// ---------------------------------------------------------------------------
__global__ __launch_bounds__(256) void table_kernel(
    const unsigned short* __restrict__ qh16, const unsigned short* __restrict__ kh16,
    const float* __restrict__ qhe, const float* __restrict__ qee,
    const float* __restrict__ khe, const float* __restrict__ kee,
    float* __restrict__ Aq, float* __restrict__ QKe,
    float* __restrict__ Bkh)
{
  const int bh = blockIdx.x >> 2;
  const int part = blockIdx.x & 3;
  const int h = bh & 7;
  const int tid = threadIdx.x;
  __shared__ float qhe_s[32][65];
  __shared__ float qee_s[16][65];
  __shared__ float khe_s[32][65];
  __shared__ float kee_s[16][65];
  __shared__ float qrow[8][68];
  __shared__ float krow[8][68];
  for (int idx = tid; idx < 96*64; idx += 256) {
    int r = idx >> 6, d = idx & 63;
    if (r < 32)      qhe_s[r][d]    = qhe[r*512 + h*64 + d];
    else if (r < 48) qee_s[r-32][d] = qee[(r-32)*512 + h*64 + d];
    else if (r < 80) khe_s[r-48][d] = khe[(r-48)*512 + h*64 + d];
    else             kee_s[r-80][d] = kee[(r-80)*512 + h*64 + d];
  }
  __syncthreads();
  const int which = tid >> 7;
  const int rem = tid & 127;
  const int lr = rem >> 4;
  const int ldp = (rem & 15) * 4;
  const int il = tid >> 5;
  const int t  = tid & 31;
  const int bhS = bh * 512;
  for (int i0 = part*128; i0 < part*128 + 128; i0 += 8) {
    {
      const unsigned short* src = which ? kh16 : qh16;
      ushort4 v4 = *reinterpret_cast<const ushort4*>(&src[(bhS + i0 + lr)*64 + ldp]);
      float* dst = which ? &krow[lr][ldp] : &qrow[lr][ldp];
      dst[0] = h2f(v4.x); dst[1] = h2f(v4.y); dst[2] = h2f(v4.z); dst[3] = h2f(v4.w);
    }
    __syncthreads();
    float accq = 0.f, acck = 0.f;
    #pragma unroll 8
    for (int d = 0; d < 64; d++) {
      accq = fmaf(qrow[il][d], qhe_s[t][d], accq);
      acck = fmaf(krow[il][d], khe_s[t][d], acck);
    }
    Aq[(bhS + i0 + il)*32 + t] = accq;
    Bkh[(bhS + i0 + il)*32 + t] = acck;
    if (t < 16) {
      float aq2 = 0.f, ak2 = 0.f;
      #pragma unroll 8
      for (int d = 0; d < 64; d++) {
        aq2 = fmaf(qrow[il][d], qee_s[t][d], aq2);
        ak2 = fmaf(krow[il][d], kee_s[t][d], ak2);
      }
      QKe[(bhS + i0 + il)*16 + t] = aq2 + ak2;
    }
    __syncthreads();
  }
}

// ---------------------------------------------------------------------------
// Fused MFMA attention v8 = v7 templated for DIAGNOSTIC ABLATION.
//   GATH: enable de16 loads + Bkh staging + bias gathers (AqF/bkhw/QKes)
//   ATOM: enable vatt/veatt LDS atomicAdds
// <1,1> = real kernel (identical math to v7). <0,0> = skeleton (MFMA +
// K/V/Pp + exp only). <1,0> = everything except atomics.
// Diagnostic variants write to scratch; counters separate per dispatch.
// ---------------------------------------------------------------------------
template<int GATH, int ATOM>
__global__ __launch_bounds__(256, 4) void attn_mfma(
    const unsigned short* __restrict__ qh16, const unsigned short* __restrict__ kh16,
    const unsigned short* __restrict__ vht,
    const float* __restrict__ Aq, const float* __restrict__ QKe,
    const float* __restrict__ Bkh,
    const float* __restrict__ vhe, const float* __restrict__ vee,
    const unsigned short* __restrict__ de16,
    unsigned short* __restrict__ outp_bf)
{
  const int blk = blockIdx.x;
  const int rt = blk >> 7;             // XCD-affinity: same-bh tiles share XCD
  const int bh = blk & 127;
  const int b = bh >> 3, h = bh & 7;
  const int i0 = rt * 64;
  const int tid = threadIdx.x;
  const int w = tid >> 6;
  const int lane = tid & 63;
  const int l15 = lane & 15, quad = lane >> 4;
  const int bhS = bh * 512;
  const int iL = w * 16 + l15;         // this lane's block-local i-row

  __shared__ union {
    struct {
      float AqF[64][34];               // 8704 B (loop, read-only)
      unsigned short QKes[64][16];     // 2048 B (loop, read-only)
    } a;
    unsigned short embT[64][72];       // 9216 B (epilogue only)
  } U;                                 // 10752 B
  __shared__ unsigned short Pp[4][16][40];    // 5120 B per-wave P tile
  __shared__ unsigned short bkhw[4][32][36];  // 9216 B per-wave Bkh f16 copy
  __shared__ float vatt[64][33];              // 8448 B (rows wave-private)
  __shared__ float veatt[64][17];             // 4352 B (rows wave-private)
  // total 37,888 B -> 4 blocks/CU

  // ---- Phase A staging (once per block)
  {
    int r = tid >> 2, c = (tid & 3) * 8;   // AqF: 64x32 f32
    float4 a0 = *reinterpret_cast<const float4*>(&Aq[(bhS + i0 + r)*32 + c]);
    float4 a1 = *reinterpret_cast<const float4*>(&Aq[(bhS + i0 + r)*32 + c + 4]);
    *reinterpret_cast<float2*>(&U.a.AqF[r][c])     = make_float2(a0.x, a0.y);
    *reinterpret_cast<float2*>(&U.a.AqF[r][c + 2]) = make_float2(a0.z, a0.w);
    *reinterpret_cast<float2*>(&U.a.AqF[r][c + 4]) = make_float2(a1.x, a1.y);
    *reinterpret_cast<float2*>(&U.a.AqF[r][c + 6]) = make_float2(a1.z, a1.w);
  }
  {
    int r = tid >> 2, t4 = (tid & 3) * 4;  // QKes: 64x16 f32 -> f16
    float4 a0 = *reinterpret_cast<const float4*>(&QKe[(bhS + i0 + r)*16 + t4]);
    ushort4 u0; u0.x = f2h(a0.x); u0.y = f2h(a0.y); u0.z = f2h(a0.z); u0.w = f2h(a0.w);
    *reinterpret_cast<ushort4*>(&U.a.QKes[r][t4]) = u0;
  }
  for (int idx = tid; idx < 64*33; idx += 256) (&vatt[0][0])[idx] = 0.f;
  for (int idx = tid; idx < 64*17; idx += 256) (&veatt[0][0])[idx] = 0.f;

  // Q as MFMA B-fragment (loop-invariant): lane holds Q[i=iL][d=quad*8..]
  f16x8 bq0 = *reinterpret_cast<const f16x8*>(&qh16[(size_t)(bhS + i0 + iL)*64 + quad*8]);
  f16x8 bq1 = *reinterpret_cast<const f16x8*>(&qh16[(size_t)(bhS + i0 + iL)*64 + 32 + quad*8]);
  __syncthreads();   // the ONLY pre-loop barrier (AqF/QKes/vatt/veatt ready)

  const size_t deBase = ((size_t)b*512 + i0 + iL) * 512;  // lane's de16 row
  // per-lane Bkh staging coords: lane covers row brow, cols bcol..bcol+15
  const int brow = lane >> 1, bcol = (lane & 1) * 16;

  f32x4 Oacc[4];
  #pragma unroll
  for (int nt = 0; nt < 4; nt++) Oacc[nt] = (f32x4){0.f,0.f,0.f,0.f};
  float sum = 0.f;

  for (int jc = 0; jc < 16; jc++) {
    const int j0 = jc * 32;

    // per-lane dist/edge (independent global loads; TLP hides latency)
    ushort4 deA = {0,0,0,0}, deB = {0,0,0,0};
    if constexpr (GATH) {
      deA = *reinterpret_cast<const ushort4*>(&de16[deBase + j0 + quad*4]);
      deB = *reinterpret_cast<const ushort4*>(&de16[deBase + j0 + 16 + quad*4]);
    }

    // stage this chunk's Bkh 32x32 into the wave's own LDS copy (f32->f16);
    // wave-in-order LDS pipe orders these writes before the gathers below.
    if constexpr (GATH) {
      const float* src = &Bkh[(size_t)(bhS + j0 + brow)*32 + bcol];
      #pragma unroll
      for (int g = 0; g < 4; g++) {
        float4 b4 = *reinterpret_cast<const float4*>(&src[g*4]);
        ushort4 u; u.x = f2h(b4.x); u.y = f2h(b4.y); u.z = f2h(b4.z); u.w = f2h(b4.w);
        *reinterpret_cast<ushort4*>(&bkhw[w][brow][bcol + g*4]) = u;
      }
    }

    // QK swapped: C[j = quad*4+r (+tile*16), i = l15]; K frags from global
    #pragma unroll
    for (int tile = 0; tile < 2; tile++) {
      const size_t krow = (size_t)(bhS + j0 + tile*16 + l15) * 64;
      f16x8 kf0 = *reinterpret_cast<const f16x8*>(&kh16[krow + quad*8]);
      f16x8 kf1 = *reinterpret_cast<const f16x8*>(&kh16[krow + 32 + quad*8]);
      f32x4 sacc = (f32x4){0.f,0.f,0.f,0.f};
      sacc = __builtin_amdgcn_mfma_f32_16x16x32_f16(kf0, bq0, sacc, 0, 0, 0);
      sacc = __builtin_amdgcn_mfma_f32_16x16x32_f16(kf1, bq1, sacc, 0, 0, 0);
      const int jbase = tile*16 + quad*4;
      const ushort4 de = tile ? deB : deA;
      ushort4 pw;

#define SCALAR_R(rr, ue, pdst)                                                \
      {                                                                       \
        const unsigned u_ = (ue);                                             \
        const int t_ = u_ & 0xFF, e_ = u_ >> 8;                               \
        float bias_ = 0.f;                                                    \
        if constexpr (GATH)                                                   \
          bias_ = U.a.AqF[iL][t_] + h2f(bkhw[w][jbase + rr][t_])              \
                + h2f(U.a.QKes[iL][e_]);                                      \
        float s_ = (sacc[rr] + bias_) * 0.125f;                               \
        float p_ = __expf(fminf(s_, 10.f));                                   \
        sum += p_;                                                            \
        if constexpr (ATOM) {                                                 \
          atomicAdd(&vatt[iL][t_], p_);                                       \
          atomicAdd(&veatt[iL][e_], p_);                                      \
        }                                                                     \
        pdst = f2h(p_);                                                       \
      }
      SCALAR_R(0, de.x, pw.x)
      SCALAR_R(1, de.y, pw.y)
      SCALAR_R(2, de.z, pw.z)
      SCALAR_R(3, de.w, pw.w)
#undef SCALAR_R

      // one aligned b64 write: P[i=l15][j = jbase..jbase+3]
      *reinterpret_cast<ushort4*>(&Pp[w][l15][jbase]) = pw;
    }

    // PV via MFMA (K=32 over this chunk); A = P (wave-private), B = V^T global
    {
      f16x8 ap = *reinterpret_cast<const f16x8*>(&Pp[w][l15][quad*8]);
      const size_t vbase = ((size_t)bh*16 + jc)*2048;
      #pragma unroll
      for (int nt = 0; nt < 4; nt++) {
        f16x8 bv = *reinterpret_cast<const f16x8*>(
            &vht[vbase + (nt*16 + l15)*32 + quad*8]);
        Oacc[nt] = __builtin_amdgcn_mfma_f32_16x16x32_f16(ap, bv, Oacc[nt], 0, 0, 0);
      }
    }
    // NO barrier: everything in this loop is wave-private or read-only.
  }

  // full row sums: combine the 4 quads sharing each i-row, then fetch the
  // sums for the C-layout output rows (quad*4 + r) via shfl.
  sum += __shfl_xor(sum, 16);
  sum += __shfl_xor(sum, 32);
  float ri[4];
  #pragma unroll
  for (int r = 0; r < 4; r++) ri[r] = 1.0f / __shfl(sum, quad*4 + r);

  __syncthreads();   // all waves done reading U.a before embT overlays it

  // stage embT [d][k]: k<32 -> vhe, 32..47 -> vee, else 0
  {
    int d = tid & 63, ks0 = (tid >> 6) * 16;
    #pragma unroll
    for (int g = 0; g < 4; g++) {
      ushort4 u;
      #pragma unroll
      for (int kk = 0; kk < 4; kk++) {
        int k = ks0 + g*4 + kk;
        float val = (k < 32) ? vhe[k*512 + h*64 + d]
                  : (k < 48) ? vee[(k-32)*512 + h*64 + d] : 0.f;
        ((unsigned short*)&u)[kk] = f2h(val);
      }
      *reinterpret_cast<ushort4*>(&U.embT[d][ks0 + g*4]) = u;
    }
  }
  __syncthreads();   // embT visible to all waves

  // mass . emb via MFMA (vatt/veatt rows are wave-private)
  {
    f16x8 am0, am1;
    #pragma unroll
    for (int j = 0; j < 8; j++) {
      am0[j] = (_Float16)vatt[iL][quad*8 + j];
      float ve = 0.f;
      if (quad < 2) ve = veatt[iL][quad*8 + j];
      am1[j] = (_Float16)ve;
    }
    #pragma unroll
    for (int nt = 0; nt < 4; nt++) {
      f16x8 be0 = *reinterpret_cast<const f16x8*>(&U.embT[nt*16 + l15][quad*8]);
      f16x8 be1 = *reinterpret_cast<const f16x8*>(&U.embT[nt*16 + l15][32 + quad*8]);
      Oacc[nt] = __builtin_amdgcn_mfma_f32_16x16x32_f16(am0, be0, Oacc[nt], 0, 0, 0);
      Oacc[nt] = __builtin_amdgcn_mfma_f32_16x16x32_f16(am1, be1, Oacc[nt], 0, 0, 0);
    }
  }

  // normalize + store bf16
  #pragma unroll
  for (int nt = 0; nt < 4; nt++) {
    #pragma unroll
    for (int r = 0; r < 4; r++) {
      int srow = i0 + w*16 + quad*4 + r;
      outp_bf[(size_t)(b*512 + srow)*512 + h*64 + nt*16 + l15] = f2bf(Oacc[nt][r] * ri[r]);
    }
  }
}

// ---------------------------------------------------------------------------
// bf16 MFMA GEMM (output proj): plain row-major fp32 C.
// ---------------------------------------------------------------------------
__global__ __launch_bounds__(256) void out_mfma(
    const unsigned short* __restrict__ X, const unsigned short* __restrict__ W,
    const float* __restrict__ bias, float* __restrict__ Y)
{
  __shared__ unsigned short As[128][40];
  __shared__ unsigned short Bs[128][40];
  const int tid = threadIdx.x;
  const int m0 = blockIdx.x * 128;
  const int n0 = blockIdx.y * 128;
  const int lane = tid & 63;
  const int w = tid >> 6;
  const int wr = w >> 1, wc = w & 1;
  const int l15 = lane & 15, quad = lane >> 4;

  const int srow = tid & 127;
  const unsigned short* srcrow = (tid < 128) ? &X[(size_t)(m0 + srow) * 512]
                                             : &W[(size_t)(n0 + srow) * 512];
  unsigned short* dstrow = (tid < 128) ? As[srow] : Bs[srow];

  f32x4 acc[4][4];
  #pragma unroll
  for (int i = 0; i < 4; i++)
    #pragma unroll
    for (int j = 0; j < 4; j++) acc[i][j] = (f32x4){0.f, 0.f, 0.f, 0.f};

  for (int k0 = 0; k0 < 512; k0 += 32) {
    #pragma unroll
    for (int u = 0; u < 4; u++) {
      uint4 t4 = *reinterpret_cast<const uint4*>(&srcrow[k0 + u * 8]);
      *reinterpret_cast<uint4*>(&dstrow[u * 8]) = t4;
    }
    __syncthreads();
    bf16x8 af[4], bfr[4];
    #pragma unroll
    for (int mt = 0; mt < 4; mt++)
      af[mt] = *reinterpret_cast<const bf16x8*>(&As[wr * 64 + mt * 16 + l15][quad * 8]);
    #pragma unroll
    for (int nt = 0; nt < 4; nt++)
      bfr[nt] = *reinterpret_cast<const bf16x8*>(&Bs[wc * 64 + nt * 16 + l15][quad * 8]);
    #pragma unroll
    for (int mt = 0; mt < 4; mt++)
      #pragma unroll
      for (int nt = 0; nt < 4; nt++)
        acc[mt][nt] = __builtin_amdgcn_mfma_f32_16x16x32_bf16(
            af[mt], bfr[nt], acc[mt][nt], 0, 0, 0);
    __syncthreads();
  }

  float bn[4];
  #pragma unroll
  for (int nt = 0; nt < 4; nt++)
    bn[nt] = bias[n0 + wc * 64 + nt * 16 + l15];
  #pragma unroll
  for (int mt = 0; mt < 4; mt++) {
    #pragma unroll
    for (int r = 0; r < 4; r++) {
      int m = m0 + wr * 64 + mt * 16 + quad * 4 + r;
      #pragma unroll
      for (int nt = 0; nt < 4; nt++) {
        int n = n0 + wc * 64 + nt * 16 + l15;
        Y[(size_t)m * 512 + n] = acc[mt][nt][r] + bn[nt];
      }
    }
  }
}

// ---------------------------------------------------------------------------
extern "C" void kernel_launch(void* const* d_in, const int* in_sizes, int n_in,
                              void* d_out, int out_size, void* d_ws, size_t ws_size,
                              hipStream_t stream) {
  (void)in_sizes; (void)n_in; (void)out_size; (void)ws_size;
  const float* q    = (const float*)d_in[0];
  const float* k    = (const float*)d_in[1];
  const float* v    = (const float*)d_in[2];
  const float* qhe  = (const float*)d_in[3];
  const float* qee  = (const float*)d_in[4];
  const float* khe  = (const float*)d_in[5];
  const float* kee  = (const float*)d_in[6];
  const float* vhe  = (const float*)d_in[7];
  const float* vee  = (const float*)d_in[8];
  const int*  dist  = (const int*)d_in[9];
  const int*  edge  = (const int*)d_in[10];
  const float* Wq = (const float*)d_in[11];
  const float* bq = (const float*)d_in[12];
  const float* Wk = (const float*)d_in[13];
  const float* bk = (const float*)d_in[14];
  const float* Wv = (const float*)d_in[15];
  const float* bv = (const float*)d_in[16];
  const float* Wo = (const float*)d_in[17];
  const float* bo = (const float*)d_in[18];

  // ---- workspace layout (bytes), total 81,788,928 ----
  char* ws = (char*)d_ws;
  unsigned short* qh16 = (unsigned short*)(ws + 0);          // 8,388,608 B
  unsigned short* kh16 = (unsigned short*)(ws + 8388608);    // 8,388,608
  unsigned short* vht  = (unsigned short*)(ws + 16777216);   // 8,388,608
  float* Aq  = (float*)(ws + 25165824);                      // 8,388,608
  float* Bkh = (float*)(ws + 33554432);                      // 8,388,608
  float* QKe = (float*)(ws + 41943040);                      // 4,194,304
  unsigned short* q_bf = (unsigned short*)(ws + 46137344);   // 8,388,608 (dead after proj_qk(q) -> reused as de16)
  unsigned short* de16 = q_bf;                               // packed dist|edge<<8
  unsigned short* k_bf = (unsigned short*)(ws + 54525952);   // 8,388,608
  unsigned short* v_bf = (unsigned short*)(ws + 62914560);   // 8,388,608 (dead after proj_v -> diag scratch)
  unsigned short* diag = v_bf;                               // diagnostic output scratch
  unsigned short* outp_bf = (unsigned short*)(ws + 71303168);// 8,388,608
  unsigned short* wq_bf = (unsigned short*)(ws + 79691776);  // 524,288
  unsigned short* wk_bf = (unsigned short*)(ws + 80216064);
  unsigned short* wv_bf = (unsigned short*)(ws + 80740352);
  unsigned short* wo_bf = (unsigned short*)(ws + 81264640);  // ends 81,788,928

  dim3 blk(256);
  hipLaunchKernelGGL(convert_bf16, dim3(13312), blk, 0, stream,
                     q, k, v, Wq, Wk, Wv, Wo,
                     q_bf, k_bf, v_bf, wq_bf, wk_bf, wv_bf, wo_bf);
  dim3 gGemm(64, 4);
  hipLaunchKernelGGL(proj_qk, gGemm, blk, 0, stream, q_bf, wq_bf, bq, qh16);
  hipLaunchKernelGGL(proj_qk, gGemm, blk, 0, stream, k_bf, wk_bf, bk, kh16);
  hipLaunchKernelGGL(proj_v,  gGemm, blk, 0, stream, v_bf, wv_bf, bv, vht);
  // q_bf dead now -> pack dist|edge into its region
  hipLaunchKernelGGL(pack_de, dim3(2048), blk, 0, stream, dist, edge, de16);
  hipLaunchKernelGGL(table_kernel, dim3(512), blk, 0, stream,
                     qh16, kh16, qhe, qee, khe, kee, Aq, QKe, Bkh);

  // ---- DIAGNOSTIC dispatches (outputs -> scratch, counters per-dispatch) --
  // V1 skeleton: no gathers, no atomics
  hipLaunchKernelGGL(HIP_KERNEL_NAME(attn_mfma<0, 0>), dim3(1024), blk, 0, stream,
                     qh16, kh16, vht, Aq, QKe, Bkh, vhe, vee, de16, diag);
  // V2: gathers but no atomics
  hipLaunchKernelGGL(HIP_KERNEL_NAME(attn_mfma<1, 0>), dim3(1024), blk, 0, stream,
                     qh16, kh16, vht, Aq, QKe, Bkh, vhe, vee, de16, diag);

  // ---- REAL attention (unchanged v7 math)
  hipLaunchKernelGGL(HIP_KERNEL_NAME(attn_mfma<1, 1>), dim3(1024), blk, 0, stream,
                     qh16, kh16, vht, Aq, QKe, Bkh, vhe, vee, de16, outp_bf);
  hipLaunchKernelGGL(out_mfma, gGemm, blk, 0, stream,
                     outp_bf, wo_bf, bo, (float*)d_out);
}

// Round 5
// 451.947 us; speedup vs baseline: 1.7479x; 1.7479x over previous
//
#include <hip/hip_runtime.h>
#include <hip/hip_fp16.h>

// Problem constants: B=16, S=512, HID=512, NH=8, DK=64, TH=32, TE=16, scale=1/8

typedef __attribute__((ext_vector_type(8))) __bf16 bf16x8;
typedef __attribute__((ext_vector_type(8))) _Float16 f16x8;
typedef __attribute__((ext_vector_type(4))) float f32x4;

static __device__ __forceinline__ unsigned short f2bf(float f) {
  unsigned u = __float_as_uint(f);
  unsigned r = (u + 0x7fffu + ((u >> 16) & 1u)) >> 16;   // RNE
  return (unsigned short)r;
}
static __device__ __forceinline__ unsigned short f2h(float f) {
  _Float16 h = (_Float16)f;
  return __builtin_bit_cast(unsigned short, h);
}
static __device__ __forceinline__ float h2f(unsigned short u) {
  _Float16 h = __builtin_bit_cast(_Float16, u);
  return (float)h;
}

// ---------------------------------------------------------------------------
// fp32 -> bf16 convert for GEMM inputs: q,k,v and Wq,Wk,Wv,Wo.
// ---------------------------------------------------------------------------
__global__ __launch_bounds__(256) void convert_bf16(
    const float* __restrict__ q, const float* __restrict__ k,
    const float* __restrict__ v, const float* __restrict__ Wq,
    const float* __restrict__ Wk, const float* __restrict__ Wv,
    const float* __restrict__ Wo,
    unsigned short* __restrict__ qb, unsigned short* __restrict__ kb,
    unsigned short* __restrict__ vb, unsigned short* __restrict__ wqb,
    unsigned short* __restrict__ wkb, unsigned short* __restrict__ wvb,
    unsigned short* __restrict__ wob)
{
  const int bid = blockIdx.x;
  const float* src; unsigned short* dst; long blk;
  if (bid < 4096)        { src = q;  dst = qb; blk = bid; }
  else if (bid < 8192)   { src = k;  dst = kb; blk = bid - 4096; }
  else if (bid < 12288)  { src = v;  dst = vb; blk = bid - 8192; }
  else {
    int r = bid - 12288; int w = r >> 8; blk = r & 255;
    src = (w == 0) ? Wq : (w == 1) ? Wk : (w == 2) ? Wv : Wo;
    dst = (w == 0) ? wqb : (w == 1) ? wkb : (w == 2) ? wvb : wob;
  }
  size_t base = (size_t)blk * 1024 + threadIdx.x * 4;
  float4 f = *reinterpret_cast<const float4*>(&src[base]);
  ushort4 o; o.x = f2bf(f.x); o.y = f2bf(f.y); o.z = f2bf(f.z); o.w = f2bf(f.w);
  *reinterpret_cast<ushort4*>(&dst[base]) = o;
}

// ---------------------------------------------------------------------------
// Pack dist|edge<<8 into uint16 (dist<32, edge<16). 2048 blocks x 256 thr x 8.
// ---------------------------------------------------------------------------
__global__ __launch_bounds__(256) void pack_de(
    const int* __restrict__ dist, const int* __restrict__ edge,
    unsigned short* __restrict__ de16)
{
  size_t base = ((size_t)blockIdx.x * 256 + threadIdx.x) * 8;
  int4 d0 = *reinterpret_cast<const int4*>(&dist[base]);
  int4 d1 = *reinterpret_cast<const int4*>(&dist[base + 4]);
  int4 e0 = *reinterpret_cast<const int4*>(&edge[base]);
  int4 e1 = *reinterpret_cast<const int4*>(&edge[base + 4]);
  ushort4 u0, u1;
  u0.x = (unsigned short)(d0.x | (e0.x << 8));
  u0.y = (unsigned short)(d0.y | (e0.y << 8));
  u0.z = (unsigned short)(d0.z | (e0.z << 8));
  u0.w = (unsigned short)(d0.w | (e0.w << 8));
  u1.x = (unsigned short)(d1.x | (e1.x << 8));
  u1.y = (unsigned short)(d1.y | (e1.y << 8));
  u1.z = (unsigned short)(d1.z | (e1.z << 8));
  u1.w = (unsigned short)(d1.w | (e1.w << 8));
  *reinterpret_cast<ushort4*>(&de16[base]) = u0;
  *reinterpret_cast<ushort4*>(&de16[base + 4]) = u1;
}

// ---------------------------------------------------------------------------
// bf16 MFMA GEMM (Q/K proj): Y = f16 head-major [B,H,S,64].
// ---------------------------------------------------------------------------
__global__ __launch_bounds__(256) void proj_qk(
    const unsigned short* __restrict__ X, const unsigned short* __restrict__ W,
    const float* __restrict__ bias, unsigned short* __restrict__ Y)
{
  __shared__ unsigned short As[128][40];
  __shared__ unsigned short Bs[128][40];
  const int tid = threadIdx.x;
  const int m0 = blockIdx.x * 128;
  const int n0 = blockIdx.y * 128;
  const int lane = tid & 63;
  const int w = tid >> 6;
  const int wr = w >> 1, wc = w & 1;
  const int l15 = lane & 15, quad = lane >> 4;

  const int srow = tid & 127;
  const unsigned short* srcrow = (tid < 128) ? &X[(size_t)(m0 + srow) * 512]
                                             : &W[(size_t)(n0 + srow) * 512];
  unsigned short* dstrow = (tid < 128) ? As[srow] : Bs[srow];

  f32x4 acc[4][4];
  #pragma unroll
  for (int i = 0; i < 4; i++)
    #pragma unroll
    for (int j = 0; j < 4; j++) acc[i][j] = (f32x4){0.f, 0.f, 0.f, 0.f};

  for (int k0 = 0; k0 < 512; k0 += 32) {
    #pragma unroll
    for (int u = 0; u < 4; u++) {
      uint4 t4 = *reinterpret_cast<const uint4*>(&srcrow[k0 + u * 8]);
      *reinterpret_cast<uint4*>(&dstrow[u * 8]) = t4;
    }
    __syncthreads();
    bf16x8 af[4], bfr[4];
    #pragma unroll
    for (int mt = 0; mt < 4; mt++)
      af[mt] = *reinterpret_cast<const bf16x8*>(&As[wr * 64 + mt * 16 + l15][quad * 8]);
    #pragma unroll
    for (int nt = 0; nt < 4; nt++)
      bfr[nt] = *reinterpret_cast<const bf16x8*>(&Bs[wc * 64 + nt * 16 + l15][quad * 8]);
    #pragma unroll
    for (int mt = 0; mt < 4; mt++)
      #pragma unroll
      for (int nt = 0; nt < 4; nt++)
        acc[mt][nt] = __builtin_amdgcn_mfma_f32_16x16x32_bf16(
            af[mt], bfr[nt], acc[mt][nt], 0, 0, 0);
    __syncthreads();
  }

  float bn[4];
  #pragma unroll
  for (int nt = 0; nt < 4; nt++)
    bn[nt] = bias[n0 + wc * 64 + nt * 16 + l15];
  #pragma unroll
  for (int mt = 0; mt < 4; mt++) {
    #pragma unroll
    for (int r = 0; r < 4; r++) {
      int m = m0 + wr * 64 + mt * 16 + quad * 4 + r;
      int bb = m >> 9, s = m & 511;
      #pragma unroll
      for (int nt = 0; nt < 4; nt++) {
        int n = n0 + wc * 64 + nt * 16 + l15;
        int h = n >> 6, d = n & 63;
        Y[(((size_t)(bb * 8 + h) * 512) + s) * 64 + d] = f2h(acc[mt][nt][r] + bn[nt]);
      }
    }
  }
}

// ---------------------------------------------------------------------------
// V proj: writes f16 TRANSPOSED+TILED vht[bh][16 chunk][64 d][32 jj].
// ---------------------------------------------------------------------------
__global__ __launch_bounds__(256) void proj_v(
    const unsigned short* __restrict__ X, const unsigned short* __restrict__ W,
    const float* __restrict__ bias, unsigned short* __restrict__ Y)
{
  __shared__ unsigned short As[128][40];
  __shared__ unsigned short Bs[128][40];
  const int tid = threadIdx.x;
  const int m0 = blockIdx.x * 128;
  const int n0 = blockIdx.y * 128;
  const int lane = tid & 63;
  const int w = tid >> 6;
  const int wr = w >> 1, wc = w & 1;
  const int l15 = lane & 15, quad = lane >> 4;

  const int srow = tid & 127;
  const unsigned short* srcrow = (tid < 128) ? &X[(size_t)(m0 + srow) * 512]
                                             : &W[(size_t)(n0 + srow) * 512];
  unsigned short* dstrow = (tid < 128) ? As[srow] : Bs[srow];

  f32x4 acc[4][4];
  #pragma unroll
  for (int i = 0; i < 4; i++)
    #pragma unroll
    for (int j = 0; j < 4; j++) acc[i][j] = (f32x4){0.f, 0.f, 0.f, 0.f};

  for (int k0 = 0; k0 < 512; k0 += 32) {
    #pragma unroll
    for (int u = 0; u < 4; u++) {
      uint4 t4 = *reinterpret_cast<const uint4*>(&srcrow[k0 + u * 8]);
      *reinterpret_cast<uint4*>(&dstrow[u * 8]) = t4;
    }
    __syncthreads();
    bf16x8 af[4], bfr[4];
    #pragma unroll
    for (int mt = 0; mt < 4; mt++)
      af[mt] = *reinterpret_cast<const bf16x8*>(&As[wr * 64 + mt * 16 + l15][quad * 8]);
    #pragma unroll
    for (int nt = 0; nt < 4; nt++)
      bfr[nt] = *reinterpret_cast<const bf16x8*>(&Bs[wc * 64 + nt * 16 + l15][quad * 8]);
    #pragma unroll
    for (int mt = 0; mt < 4; mt++)
      #pragma unroll
      for (int nt = 0; nt < 4; nt++)
        acc[mt][nt] = __builtin_amdgcn_mfma_f32_16x16x32_bf16(
            af[mt], bfr[nt], acc[mt][nt], 0, 0, 0);
    __syncthreads();
  }

  float bn[4];
  #pragma unroll
  for (int nt = 0; nt < 4; nt++)
    bn[nt] = bias[n0 + wc * 64 + nt * 16 + l15];
  #pragma unroll
  for (int mt = 0; mt < 4; mt++) {
    #pragma unroll
    for (int r = 0; r < 4; r++) {
      int m = m0 + wr * 64 + mt * 16 + quad * 4 + r;
      int bb = m >> 9, s = m & 511;
      #pragma unroll
      for (int nt = 0; nt < 4; nt++) {
        int n = n0 + wc * 64 + nt * 16 + l15;
        int h = n >> 6, d = n & 63;
        size_t bh = (size_t)(bb * 8 + h);
        Y[(bh * 16 + (s >> 5)) * 2048 + d * 32 + (s & 31)] = f2h(acc[mt][nt][r] + bn[nt]);
      }
    }
  }
}

// ---------------------------------------------------------------------------
// Bias tables (f16 q/k inputs), block = (bh, quarter of rows). 512 blocks.
// ---------------------------------------------------------------------------
__global__ __launch_bounds__(256) void table_kernel(
    const unsigned short* __restrict__ qh16, const unsigned short* __restrict__ kh16,
    const float* __restrict__ qhe, const float* __restrict__ qee,
    const float* __restrict__ khe, const float* __restrict__ kee,
    float* __restrict__ Aq, float* __restrict__ QKe,
    float* __restrict__ Bkh)
{
  const int bh = blockIdx.x >> 2;
  const int part = blockIdx.x & 3;
  const int h = bh & 7;
  const int tid = threadIdx.x;
  __shared__ float qhe_s[32][65];
  __shared__ float qee_s[16][65];
  __shared__ float khe_s[32][65];
  __shared__ float kee_s[16][65];
  __shared__ float qrow[8][68];
  __shared__ float krow[8][68];
  for (int idx = tid; idx < 96*64; idx += 256) {
    int r = idx >> 6, d = idx & 63;
    if (r < 32)      qhe_s[r][d]    = qhe[r*512 + h*64 + d];
    else if (r < 48) qee_s[r-32][d] = qee[(r-32)*512 + h*64 + d];
    else if (r < 80) khe_s[r-48][d] = khe[(r-48)*512 + h*64 + d];
    else             kee_s[r-80][d] = kee[(r-80)*512 + h*64 + d];
  }
  __syncthreads();
  const int which = tid >> 7;
  const int rem = tid & 127;
  const int lr = rem >> 4;
  const int ldp = (rem & 15) * 4;
  const int il = tid >> 5;
  const int t  = tid & 31;
  const int bhS = bh * 512;
  for (int i0 = part*128; i0 < part*128 + 128; i0 += 8) {
    {
      const unsigned short* src = which ? kh16 : qh16;
      ushort4 v4 = *reinterpret_cast<const ushort4*>(&src[(bhS + i0 + lr)*64 + ldp]);
      float* dst = which ? &krow[lr][ldp] : &qrow[lr][ldp];
      dst[0] = h2f(v4.x); dst[1] = h2f(v4.y); dst[2] = h2f(v4.z); dst[3] = h2f(v4.w);
    }
    __syncthreads();
    float accq = 0.f, acck = 0.f;
    #pragma unroll 8
    for (int d = 0; d < 64; d++) {
      accq = fmaf(qrow[il][d], qhe_s[t][d], accq);
      acck = fmaf(krow[il][d], khe_s[t][d], acck);
    }
    Aq[(bhS + i0 + il)*32 + t] = accq;
    Bkh[(bhS + i0 + il)*32 + t] = acck;
    if (t < 16) {
      float aq2 = 0.f, ak2 = 0.f;
      #pragma unroll 8
      for (int d = 0; d < 64; d++) {
        aq2 = fmaf(qrow[il][d], qee_s[t][d], aq2);
        ak2 = fmaf(krow[il][d], kee_s[t][d], ak2);
      }
      QKe[(bhS + i0 + il)*16 + t] = aq2 + ak2;
    }
    __syncthreads();
  }
}

// ---------------------------------------------------------------------------
// Fused MFMA attention v9: NO LDS ATOMICS.
// R4 ablation: skeleton+gathers ~135 µs combined, full kernel 372 µs ->
// the 2 LDS fp32 atomicAdds per score element cost ~240 µs (~65%). LDS
// atomic RMW is throughput-bound (~2.5 cyc/lane), not contention-bound.
// v9 accumulates hop/edge masses in PER-LANE REGISTERS (hb[32], eb[16]):
//  - each lane's 8 scores/chunk all belong to its OWN row iL, so bins are
//    lane-private; update = fully-unrolled compare-select-add (VALU, which
//    is 94% idle) with static indices (stays in registers).
//  - end: one-time cross-quad shfl_xor(16/32) reduction -> every lane has
//    all 48 bins of its row; epilogue MFMA A-frags via static cndmask.
// vatt/veatt LDS arrays + zero-init deleted; LDS 37.9 -> 25.1 KB.
// Barrier-free main loop unchanged from v7.
// ---------------------------------------------------------------------------
__global__ __launch_bounds__(256, 4) void attn_mfma(
    const unsigned short* __restrict__ qh16, const unsigned short* __restrict__ kh16,
    const unsigned short* __restrict__ vht,
    const float* __restrict__ Aq, const float* __restrict__ QKe,
    const float* __restrict__ Bkh,
    const float* __restrict__ vhe, const float* __restrict__ vee,
    const unsigned short* __restrict__ de16,
    unsigned short* __restrict__ outp_bf)
{
  const int blk = blockIdx.x;
  const int rt = blk >> 7;             // XCD-affinity: same-bh tiles share XCD
  const int bh = blk & 127;
  const int b = bh >> 3, h = bh & 7;
  const int i0 = rt * 64;
  const int tid = threadIdx.x;
  const int w = tid >> 6;
  const int lane = tid & 63;
  const int l15 = lane & 15, quad = lane >> 4;
  const int bhS = bh * 512;
  const int iL = w * 16 + l15;         // this lane's block-local i-row

  __shared__ union {
    struct {
      float AqF[64][34];               // 8704 B (loop, read-only)
      unsigned short QKes[64][16];     // 2048 B (loop, read-only)
    } a;
    unsigned short embT[64][72];       // 9216 B (epilogue only)
  } U;                                 // 10752 B
  __shared__ unsigned short Pp[4][16][40];    // 5120 B per-wave P tile
  __shared__ unsigned short bkhw[4][32][36];  // 9216 B per-wave Bkh f16 copy
  // total 25,088 B

  // ---- Phase A staging (once per block)
  {
    int r = tid >> 2, c = (tid & 3) * 8;   // AqF: 64x32 f32
    float4 a0 = *reinterpret_cast<const float4*>(&Aq[(bhS + i0 + r)*32 + c]);
    float4 a1 = *reinterpret_cast<const float4*>(&Aq[(bhS + i0 + r)*32 + c + 4]);
    *reinterpret_cast<float2*>(&U.a.AqF[r][c])     = make_float2(a0.x, a0.y);
    *reinterpret_cast<float2*>(&U.a.AqF[r][c + 2]) = make_float2(a0.z, a0.w);
    *reinterpret_cast<float2*>(&U.a.AqF[r][c + 4]) = make_float2(a1.x, a1.y);
    *reinterpret_cast<float2*>(&U.a.AqF[r][c + 6]) = make_float2(a1.z, a1.w);
  }
  {
    int r = tid >> 2, t4 = (tid & 3) * 4;  // QKes: 64x16 f32 -> f16
    float4 a0 = *reinterpret_cast<const float4*>(&QKe[(bhS + i0 + r)*16 + t4]);
    ushort4 u0; u0.x = f2h(a0.x); u0.y = f2h(a0.y); u0.z = f2h(a0.z); u0.w = f2h(a0.w);
    *reinterpret_cast<ushort4*>(&U.a.QKes[r][t4]) = u0;
  }

  // Q as MFMA B-fragment (loop-invariant): lane holds Q[i=iL][d=quad*8..]
  f16x8 bq0 = *reinterpret_cast<const f16x8*>(&qh16[(size_t)(bhS + i0 + iL)*64 + quad*8]);
  f16x8 bq1 = *reinterpret_cast<const f16x8*>(&qh16[(size_t)(bhS + i0 + iL)*64 + 32 + quad*8]);
  __syncthreads();   // the ONLY pre-loop barrier (AqF/QKes ready)

  const size_t deBase = ((size_t)b*512 + i0 + iL) * 512;  // lane's de16 row
  // per-lane Bkh staging coords: lane covers row brow, cols bcol..bcol+15
  const int brow = lane >> 1, bcol = (lane & 1) * 16;

  f32x4 Oacc[4];
  #pragma unroll
  for (int nt = 0; nt < 4; nt++) Oacc[nt] = (f32x4){0.f,0.f,0.f,0.f};
  float sum = 0.f;

  // per-lane register mass bins for row iL (this quad's j-slice)
  float hb[32], eb[16];
  #pragma unroll
  for (int t = 0; t < 32; t++) hb[t] = 0.f;
  #pragma unroll
  for (int t = 0; t < 16; t++) eb[t] = 0.f;

  for (int jc = 0; jc < 16; jc++) {
    const int j0 = jc * 32;

    // per-lane dist/edge (independent global loads; TLP hides latency)
    ushort4 deA = *reinterpret_cast<const ushort4*>(&de16[deBase + j0 + quad*4]);
    ushort4 deB = *reinterpret_cast<const ushort4*>(&de16[deBase + j0 + 16 + quad*4]);

    // stage this chunk's Bkh 32x32 into the wave's own LDS copy (f32->f16);
    // wave-in-order LDS pipe orders these writes before the gathers below.
    {
      const float* src = &Bkh[(size_t)(bhS + j0 + brow)*32 + bcol];
      #pragma unroll
      for (int g = 0; g < 4; g++) {
        float4 b4 = *reinterpret_cast<const float4*>(&src[g*4]);
        ushort4 u; u.x = f2h(b4.x); u.y = f2h(b4.y); u.z = f2h(b4.z); u.w = f2h(b4.w);
        *reinterpret_cast<ushort4*>(&bkhw[w][brow][bcol + g*4]) = u;
      }
    }

    // QK swapped: C[j = quad*4+r (+tile*16), i = l15]; K frags from global
    #pragma unroll
    for (int tile = 0; tile < 2; tile++) {
      const size_t krow = (size_t)(bhS + j0 + tile*16 + l15) * 64;
      f16x8 kf0 = *reinterpret_cast<const f16x8*>(&kh16[krow + quad*8]);
      f16x8 kf1 = *reinterpret_cast<const f16x8*>(&kh16[krow + 32 + quad*8]);
      f32x4 sacc = (f32x4){0.f,0.f,0.f,0.f};
      sacc = __builtin_amdgcn_mfma_f32_16x16x32_f16(kf0, bq0, sacc, 0, 0, 0);
      sacc = __builtin_amdgcn_mfma_f32_16x16x32_f16(kf1, bq1, sacc, 0, 0, 0);
      const int jbase = tile*16 + quad*4;
      const ushort4 de = tile ? deB : deA;
      ushort4 pw;

#define SCALAR_R(rr, ue, pdst)                                                \
      {                                                                       \
        const unsigned u_ = (ue);                                             \
        const int t_ = u_ & 0xFF, e_ = u_ >> 8;                               \
        float bias_ = U.a.AqF[iL][t_] + h2f(bkhw[w][jbase + rr][t_])          \
                    + h2f(U.a.QKes[iL][e_]);                                  \
        float s_ = (sacc[rr] + bias_) * 0.125f;                               \
        float p_ = __expf(fminf(s_, 10.f));                                   \
        sum += p_;                                                            \
        _Pragma("unroll")                                                     \
        for (int t = 0; t < 32; t++) hb[t] += (t == t_) ? p_ : 0.f;           \
        _Pragma("unroll")                                                     \
        for (int t = 0; t < 16; t++) eb[t] += (t == e_) ? p_ : 0.f;           \
        pdst = f2h(p_);                                                       \
      }
      SCALAR_R(0, de.x, pw.x)
      SCALAR_R(1, de.y, pw.y)
      SCALAR_R(2, de.z, pw.z)
      SCALAR_R(3, de.w, pw.w)
#undef SCALAR_R

      // one aligned b64 write: P[i=l15][j = jbase..jbase+3]
      *reinterpret_cast<ushort4*>(&Pp[w][l15][jbase]) = pw;
    }

    // PV via MFMA (K=32 over this chunk); A = P (wave-private), B = V^T global
    {
      f16x8 ap = *reinterpret_cast<const f16x8*>(&Pp[w][l15][quad*8]);
      const size_t vbase = ((size_t)bh*16 + jc)*2048;
      #pragma unroll
      for (int nt = 0; nt < 4; nt++) {
        f16x8 bv = *reinterpret_cast<const f16x8*>(
            &vht[vbase + (nt*16 + l15)*32 + quad*8]);
        Oacc[nt] = __builtin_amdgcn_mfma_f32_16x16x32_f16(ap, bv, Oacc[nt], 0, 0, 0);
      }
    }
    // NO barrier: everything in this loop is wave-private or read-only.
  }

  // cross-quad reduce: combine the 4 quads' j-slices of row iL.
  sum += __shfl_xor(sum, 16);
  sum += __shfl_xor(sum, 32);
  #pragma unroll
  for (int t = 0; t < 32; t++) {
    hb[t] += __shfl_xor(hb[t], 16);
    hb[t] += __shfl_xor(hb[t], 32);
  }
  #pragma unroll
  for (int t = 0; t < 16; t++) {
    eb[t] += __shfl_xor(eb[t], 16);
    eb[t] += __shfl_xor(eb[t], 32);
  }
  float ri[4];
  #pragma unroll
  for (int r = 0; r < 4; r++) ri[r] = 1.0f / __shfl(sum, quad*4 + r);

  __syncthreads();   // all waves done reading U.a before embT overlays it

  // stage embT [d][k]: k<32 -> vhe, 32..47 -> vee, else 0
  {
    int d = tid & 63, ks0 = (tid >> 6) * 16;
    #pragma unroll
    for (int g = 0; g < 4; g++) {
      ushort4 u;
      #pragma unroll
      for (int kk = 0; kk < 4; kk++) {
        int k = ks0 + g*4 + kk;
        float val = (k < 32) ? vhe[k*512 + h*64 + d]
                  : (k < 48) ? vee[(k-32)*512 + h*64 + d] : 0.f;
        ((unsigned short*)&u)[kk] = f2h(val);
      }
      *reinterpret_cast<ushort4*>(&U.embT[d][ks0 + g*4]) = u;
    }
  }
  __syncthreads();   // embT visible to all waves

  // mass . emb via MFMA; A-frags built from register bins (static selects)
  {
    f16x8 am0, am1;
    #pragma unroll
    for (int j = 0; j < 8; j++) {
      float hv = (quad == 0) ? hb[j]
               : (quad == 1) ? hb[8 + j]
               : (quad == 2) ? hb[16 + j] : hb[24 + j];
      am0[j] = (_Float16)hv;
      float ve = (quad == 0) ? eb[j]
               : (quad == 1) ? eb[8 + j] : 0.f;
      am1[j] = (_Float16)ve;
    }
    #pragma unroll
    for (int nt = 0; nt < 4; nt++) {
      f16x8 be0 = *reinterpret_cast<const f16x8*>(&U.embT[nt*16 + l15][quad*8]);
      f16x8 be1 = *reinterpret_cast<const f16x8*>(&U.embT[nt*16 + l15][32 + quad*8]);
      Oacc[nt] = __builtin_amdgcn_mfma_f32_16x16x32_f16(am0, be0, Oacc[nt], 0, 0, 0);
      Oacc[nt] = __builtin_amdgcn_mfma_f32_16x16x32_f16(am1, be1, Oacc[nt], 0, 0, 0);
    }
  }

  // normalize + store bf16
  #pragma unroll
  for (int nt = 0; nt < 4; nt++) {
    #pragma unroll
    for (int r = 0; r < 4; r++) {
      int srow = i0 + w*16 + quad*4 + r;
      outp_bf[(size_t)(b*512 + srow)*512 + h*64 + nt*16 + l15] = f2bf(Oacc[nt][r] * ri[r]);
    }
  }
}

// ---------------------------------------------------------------------------
// bf16 MFMA GEMM (output proj): plain row-major fp32 C.
// ---------------------------------------------------------------------------
__global__ __launch_bounds__(256) void out_mfma(
    const unsigned short* __restrict__ X, const unsigned short* __restrict__ W,
    const float* __restrict__ bias, float* __restrict__ Y)
{
  __shared__ unsigned short As[128][40];
  __shared__ unsigned short Bs[128][40];
  const int tid = threadIdx.x;
  const int m0 = blockIdx.x * 128;
  const int n0 = blockIdx.y * 128;
  const int lane = tid & 63;
  const int w = tid >> 6;
  const int wr = w >> 1, wc = w & 1;
  const int l15 = lane & 15, quad = lane >> 4;

  const int srow = tid & 127;
  const unsigned short* srcrow = (tid < 128) ? &X[(size_t)(m0 + srow) * 512]
                                             : &W[(size_t)(n0 + srow) * 512];
  unsigned short* dstrow = (tid < 128) ? As[srow] : Bs[srow];

  f32x4 acc[4][4];
  #pragma unroll
  for (int i = 0; i < 4; i++)
    #pragma unroll
    for (int j = 0; j < 4; j++) acc[i][j] = (f32x4){0.f, 0.f, 0.f, 0.f};

  for (int k0 = 0; k0 < 512; k0 += 32) {
    #pragma unroll
    for (int u = 0; u < 4; u++) {
      uint4 t4 = *reinterpret_cast<const uint4*>(&srcrow[k0 + u * 8]);
      *reinterpret_cast<uint4*>(&dstrow[u * 8]) = t4;
    }
    __syncthreads();
    bf16x8 af[4], bfr[4];
    #pragma unroll
    for (int mt = 0; mt < 4; mt++)
      af[mt] = *reinterpret_cast<const bf16x8*>(&As[wr * 64 + mt * 16 + l15][quad * 8]);
    #pragma unroll
    for (int nt = 0; nt < 4; nt++)
      bfr[nt] = *reinterpret_cast<const bf16x8*>(&Bs[wc * 64 + nt * 16 + l15][quad * 8]);
    #pragma unroll
    for (int mt = 0; mt < 4; mt++)
      #pragma unroll
      for (int nt = 0; nt < 4; nt++)
        acc[mt][nt] = __builtin_amdgcn_mfma_f32_16x16x32_bf16(
            af[mt], bfr[nt], acc[mt][nt], 0, 0, 0);
    __syncthreads();
  }

  float bn[4];
  #pragma unroll
  for (int nt = 0; nt < 4; nt++)
    bn[nt] = bias[n0 + wc * 64 + nt * 16 + l15];
  #pragma unroll
  for (int mt = 0; mt < 4; mt++) {
    #pragma unroll
    for (int r = 0; r < 4; r++) {
      int m = m0 + wr * 64 + mt * 16 + quad * 4 + r;
      #pragma unroll
      for (int nt = 0; nt < 4; nt++) {
        int n = n0 + wc * 64 + nt * 16 + l15;
        Y[(size_t)m * 512 + n] = acc[mt][nt][r] + bn[nt];
      }
    }
  }
}

// ---------------------------------------------------------------------------
extern "C" void kernel_launch(void* const* d_in, const int* in_sizes, int n_in,
                              void* d_out, int out_size, void* d_ws, size_t ws_size,
                              hipStream_t stream) {
  (void)in_sizes; (void)n_in; (void)out_size; (void)ws_size;
  const float* q    = (const float*)d_in[0];
  const float* k    = (const float*)d_in[1];
  const float* v    = (const float*)d_in[2];
  const float* qhe  = (const float*)d_in[3];
  const float* qee  = (const float*)d_in[4];
  const float* khe  = (const float*)d_in[5];
  const float* kee  = (const float*)d_in[6];
  const float* vhe  = (const float*)d_in[7];
  const float* vee  = (const float*)d_in[8];
  const int*  dist  = (const int*)d_in[9];
  const int*  edge  = (const int*)d_in[10];
  const float* Wq = (const float*)d_in[11];
  const float* bq = (const float*)d_in[12];
  const float* Wk = (const float*)d_in[13];
  const float* bk = (const float*)d_in[14];
  const float* Wv = (const float*)d_in[15];
  const float* bv = (const float*)d_in[16];
  const float* Wo = (const float*)d_in[17];
  const float* bo = (const float*)d_in[18];

  // ---- workspace layout (bytes), total 81,788,928 ----
  char* ws = (char*)d_ws;
  unsigned short* qh16 = (unsigned short*)(ws + 0);          // 8,388,608 B
  unsigned short* kh16 = (unsigned short*)(ws + 8388608);    // 8,388,608
  unsigned short* vht  = (unsigned short*)(ws + 16777216);   // 8,388,608
  float* Aq  = (float*)(ws + 25165824);                      // 8,388,608
  float* Bkh = (float*)(ws + 33554432);                      // 8,388,608
  float* QKe = (float*)(ws + 41943040);                      // 4,194,304
  unsigned short* q_bf = (unsigned short*)(ws + 46137344);   // 8,388,608 (dead after proj_qk(q) -> reused as de16)
  unsigned short* de16 = q_bf;                               // packed dist|edge<<8
  unsigned short* k_bf = (unsigned short*)(ws + 54525952);   // 8,388,608
  unsigned short* v_bf = (unsigned short*)(ws + 62914560);   // 8,388,608
  unsigned short* outp_bf = (unsigned short*)(ws + 71303168);// 8,388,608
  unsigned short* wq_bf = (unsigned short*)(ws + 79691776);  // 524,288
  unsigned short* wk_bf = (unsigned short*)(ws + 80216064);
  unsigned short* wv_bf = (unsigned short*)(ws + 80740352);
  unsigned short* wo_bf = (unsigned short*)(ws + 81264640);  // ends 81,788,928

  dim3 blk(256);
  hipLaunchKernelGGL(convert_bf16, dim3(13312), blk, 0, stream,
                     q, k, v, Wq, Wk, Wv, Wo,
                     q_bf, k_bf, v_bf, wq_bf, wk_bf, wv_bf, wo_bf);
  dim3 gGemm(64, 4);
  hipLaunchKernelGGL(proj_qk, gGemm, blk, 0, stream, q_bf, wq_bf, bq, qh16);
  hipLaunchKernelGGL(proj_qk, gGemm, blk, 0, stream, k_bf, wk_bf, bk, kh16);
  hipLaunchKernelGGL(proj_v,  gGemm, blk, 0, stream, v_bf, wv_bf, bv, vht);
  // q_bf dead now -> pack dist|edge into its region
  hipLaunchKernelGGL(pack_de, dim3(2048), blk, 0, stream, dist, edge, de16);
  hipLaunchKernelGGL(table_kernel, dim3(512), blk, 0, stream,
                     qh16, kh16, qhe, qee, khe, kee, Aq, QKe, Bkh);
  hipLaunchKernelGGL(attn_mfma, dim3(1024), blk, 0, stream,
                     qh16, kh16, vht, Aq, QKe, Bkh, vhe, vee, de16, outp_bf);
  hipLaunchKernelGGL(out_mfma, gGemm, blk, 0, stream,
                     outp_bf, wo_bf, bo, (float*)d_out);
}

// Round 6
// 401.330 us; speedup vs baseline: 1.9684x; 1.1261x over previous
//
#include <hip/hip_runtime.h>
#include <hip/hip_fp16.h>

// Problem constants: B=16, S=512, HID=512, NH=8, DK=64, TH=32, TE=16, scale=1/8

typedef __attribute__((ext_vector_type(8))) __bf16 bf16x8;
typedef __attribute__((ext_vector_type(8))) _Float16 f16x8;
typedef __attribute__((ext_vector_type(4))) float f32x4;

static __device__ __forceinline__ unsigned short f2bf(float f) {
  unsigned u = __float_as_uint(f);
  unsigned r = (u + 0x7fffu + ((u >> 16) & 1u)) >> 16;   // RNE
  return (unsigned short)r;
}
static __device__ __forceinline__ unsigned short f2h(float f) {
  _Float16 h = (_Float16)f;
  return __builtin_bit_cast(unsigned short, h);
}
static __device__ __forceinline__ float h2f(unsigned short u) {
  _Float16 h = __builtin_bit_cast(_Float16, u);
  return (float)h;
}

// ---------------------------------------------------------------------------
// Pack dist|edge<<8 into uint16 (dist<32, edge<16). 2048 blocks x 256 thr x 8.
// ---------------------------------------------------------------------------
__global__ __launch_bounds__(256) void pack_de(
    const int* __restrict__ dist, const int* __restrict__ edge,
    unsigned short* __restrict__ de16)
{
  size_t base = ((size_t)blockIdx.x * 256 + threadIdx.x) * 8;
  int4 d0 = *reinterpret_cast<const int4*>(&dist[base]);
  int4 d1 = *reinterpret_cast<const int4*>(&dist[base + 4]);
  int4 e0 = *reinterpret_cast<const int4*>(&edge[base]);
  int4 e1 = *reinterpret_cast<const int4*>(&edge[base + 4]);
  ushort4 u0, u1;
  u0.x = (unsigned short)(d0.x | (e0.x << 8));
  u0.y = (unsigned short)(d0.y | (e0.y << 8));
  u0.z = (unsigned short)(d0.z | (e0.z << 8));
  u0.w = (unsigned short)(d0.w | (e0.w << 8));
  u1.x = (unsigned short)(d1.x | (e1.x << 8));
  u1.y = (unsigned short)(d1.y | (e1.y << 8));
  u1.z = (unsigned short)(d1.z | (e1.z << 8));
  u1.w = (unsigned short)(d1.w | (e1.w << 8));
  *reinterpret_cast<ushort4*>(&de16[base]) = u0;
  *reinterpret_cast<ushort4*>(&de16[base + 4]) = u1;
}

// ---------------------------------------------------------------------------
// Fused Q/K/V projection (blockIdx.z selects which). Reads f32 X and f32 W
// directly (f32->bf16 RNE conversion folded into staging -> convert_bf16
// kernel deleted). Register prefetch: K-tile k+1's global loads issue during
// tile k's MFMAs. 768 blocks -> 3 blocks/CU (was 3 serial launches @1/CU).
//   z=0: Y=qh16 head-major f16 [B,H,S,64]
//   z=1: Y=kh16 head-major f16
//   z=2: Y=vht transposed+tiled f16 [bh][16][64][32]
// ---------------------------------------------------------------------------
__global__ __launch_bounds__(256) void proj_fused(
    const float* __restrict__ qf, const float* __restrict__ kf,
    const float* __restrict__ vf,
    const float* __restrict__ Wq, const float* __restrict__ Wk,
    const float* __restrict__ Wv,
    const float* __restrict__ bq, const float* __restrict__ bk,
    const float* __restrict__ bv,
    unsigned short* __restrict__ qh16, unsigned short* __restrict__ kh16,
    unsigned short* __restrict__ vht)
{
  const int z = blockIdx.z;
  const float* X = (z == 0) ? qf : (z == 1) ? kf : vf;
  const float* W = (z == 0) ? Wq : (z == 1) ? Wk : Wv;
  const float* bias = (z == 0) ? bq : (z == 1) ? bk : bv;
  unsigned short* Y = (z == 0) ? qh16 : (z == 1) ? kh16 : vht;

  __shared__ unsigned short As[128][40];
  __shared__ unsigned short Bs[128][40];
  const int tid = threadIdx.x;
  const int m0 = blockIdx.x * 128;
  const int n0 = blockIdx.y * 128;
  const int lane = tid & 63;
  const int w = tid >> 6;
  const int wr = w >> 1, wc = w & 1;
  const int l15 = lane & 15, quad = lane >> 4;

  const int srow = tid & 127;
  const float* srcrow = (tid < 128) ? &X[(size_t)(m0 + srow) * 512]
                                    : &W[(size_t)(n0 + srow) * 512];
  unsigned short* dstrow = (tid < 128) ? As[srow] : Bs[srow];

  f32x4 acc[4][4];
  #pragma unroll
  for (int i = 0; i < 4; i++)
    #pragma unroll
    for (int j = 0; j < 4; j++) acc[i][j] = (f32x4){0.f, 0.f, 0.f, 0.f};

  // prefetch K-tile 0 (8 x float4 = this thread's 32-element k-slice)
  float4 pf[8];
  #pragma unroll
  for (int u = 0; u < 8; u++)
    pf[u] = *reinterpret_cast<const float4*>(&srcrow[u * 4]);

  for (int k0 = 0; k0 < 512; k0 += 32) {
    __syncthreads();   // previous iter's MFMA LDS reads done
    #pragma unroll
    for (int u = 0; u < 4; u++) {
      float4 a = pf[2*u], b2 = pf[2*u + 1];
      ushort4 lo, hi;
      lo.x = f2bf(a.x);  lo.y = f2bf(a.y);  lo.z = f2bf(a.z);  lo.w = f2bf(a.w);
      hi.x = f2bf(b2.x); hi.y = f2bf(b2.y); hi.z = f2bf(b2.z); hi.w = f2bf(b2.w);
      *reinterpret_cast<ushort4*>(&dstrow[u * 8]) = lo;
      *reinterpret_cast<ushort4*>(&dstrow[u * 8 + 4]) = hi;
    }
    __syncthreads();
    if (k0 < 480) {
      #pragma unroll
      for (int u = 0; u < 8; u++)
        pf[u] = *reinterpret_cast<const float4*>(&srcrow[k0 + 32 + u * 4]);
    }
    bf16x8 af[4], bfr[4];
    #pragma unroll
    for (int mt = 0; mt < 4; mt++)
      af[mt] = *reinterpret_cast<const bf16x8*>(&As[wr * 64 + mt * 16 + l15][quad * 8]);
    #pragma unroll
    for (int nt = 0; nt < 4; nt++)
      bfr[nt] = *reinterpret_cast<const bf16x8*>(&Bs[wc * 64 + nt * 16 + l15][quad * 8]);
    #pragma unroll
    for (int mt = 0; mt < 4; mt++)
      #pragma unroll
      for (int nt = 0; nt < 4; nt++)
        acc[mt][nt] = __builtin_amdgcn_mfma_f32_16x16x32_bf16(
            af[mt], bfr[nt], acc[mt][nt], 0, 0, 0);
  }

  float bn[4];
  #pragma unroll
  for (int nt = 0; nt < 4; nt++)
    bn[nt] = bias[n0 + wc * 64 + nt * 16 + l15];

  if (z < 2) {
    #pragma unroll
    for (int mt = 0; mt < 4; mt++) {
      #pragma unroll
      for (int r = 0; r < 4; r++) {
        int m = m0 + wr * 64 + mt * 16 + quad * 4 + r;
        int bb = m >> 9, s = m & 511;
        #pragma unroll
        for (int nt = 0; nt < 4; nt++) {
          int n = n0 + wc * 64 + nt * 16 + l15;
          int h = n >> 6, d = n & 63;
          Y[(((size_t)(bb * 8 + h) * 512) + s) * 64 + d] = f2h(acc[mt][nt][r] + bn[nt]);
        }
      }
    }
  } else {
    #pragma unroll
    for (int mt = 0; mt < 4; mt++) {
      #pragma unroll
      for (int r = 0; r < 4; r++) {
        int m = m0 + wr * 64 + mt * 16 + quad * 4 + r;
        int bb = m >> 9, s = m & 511;
        #pragma unroll
        for (int nt = 0; nt < 4; nt++) {
          int n = n0 + wc * 64 + nt * 16 + l15;
          int h = n >> 6, d = n & 63;
          size_t bh = (size_t)(bb * 8 + h);
          Y[(bh * 16 + (s >> 5)) * 2048 + d * 32 + (s & 31)] = f2h(acc[mt][nt][r] + bn[nt]);
        }
      }
    }
  }
}

// ---------------------------------------------------------------------------
// Bias tables via MFMA (replaces scalar table_kernel, est. 60-150 us of
// LDS-pipe serialization). Three tiny GEMMs, K=64:
//   Aq[i][t]   = qh[i,:].qhe[t,:]          (f32 out, 32 cols)
//   Bkh[j][t]  = kh[j,:].khe[t,:]          (f16 out, 32 cols)
//   QKe[i][e]  = qh[i,:].qee[e,:] + kh[i,:].kee[e,:]   (f16 out, 16 cols)
// Operands straight from global (no LDS, no barriers). Block = (bh, quarter),
// 512 blocks x 4 waves; wave handles 32 rows = 2 m-tiles, 24 MFMAs.
// ---------------------------------------------------------------------------
static __device__ __forceinline__ f16x8 ldembB(const float* __restrict__ T,
                                               int row, int off) {
  float4 a = *reinterpret_cast<const float4*>(&T[(size_t)row * 512 + off]);
  float4 b = *reinterpret_cast<const float4*>(&T[(size_t)row * 512 + off + 4]);
  f16x8 r;
  r[0] = (_Float16)a.x; r[1] = (_Float16)a.y; r[2] = (_Float16)a.z; r[3] = (_Float16)a.w;
  r[4] = (_Float16)b.x; r[5] = (_Float16)b.y; r[6] = (_Float16)b.z; r[7] = (_Float16)b.w;
  return r;
}

__global__ __launch_bounds__(256) void table_mfma(
    const unsigned short* __restrict__ qh16, const unsigned short* __restrict__ kh16,
    const float* __restrict__ qhe, const float* __restrict__ qee,
    const float* __restrict__ khe, const float* __restrict__ kee,
    float* __restrict__ Aq, unsigned short* __restrict__ QKe16,
    unsigned short* __restrict__ Bkh16)
{
  const int bh = blockIdx.x >> 2;
  const int part = blockIdx.x & 3;
  const int h = bh & 7;
  const int tid = threadIdx.x;
  const int w = tid >> 6;
  const int lane = tid & 63;
  const int l15 = lane & 15, quad = lane >> 4;
  const int bhS = bh * 512;
  const int ib = part * 128 + w * 32;          // wave's 32 rows
  const int hoff = h * 64;

  // B-fragments from emb tables (loop-invariant, f32 -> f16)
  f16x8 qheB[2][2], kheB[2][2], qeeB[2], keeB[2];
  #pragma unroll
  for (int nt = 0; nt < 2; nt++)
    #pragma unroll
    for (int kk = 0; kk < 2; kk++) {
      qheB[nt][kk] = ldembB(qhe, nt * 16 + l15, hoff + kk * 32 + quad * 8);
      kheB[nt][kk] = ldembB(khe, nt * 16 + l15, hoff + kk * 32 + quad * 8);
    }
  #pragma unroll
  for (int kk = 0; kk < 2; kk++) {
    qeeB[kk] = ldembB(qee, l15, hoff + kk * 32 + quad * 8);
    keeB[kk] = ldembB(kee, l15, hoff + kk * 32 + quad * 8);
  }

  f32x4 aacc[2][2], kacc[2][2], eacc[2];
  #pragma unroll
  for (int mt = 0; mt < 2; mt++) {
    #pragma unroll
    for (int nt = 0; nt < 2; nt++) {
      aacc[mt][nt] = (f32x4){0.f, 0.f, 0.f, 0.f};
      kacc[mt][nt] = (f32x4){0.f, 0.f, 0.f, 0.f};
    }
    eacc[mt] = (f32x4){0.f, 0.f, 0.f, 0.f};
  }

  #pragma unroll
  for (int mt = 0; mt < 2; mt++) {
    #pragma unroll
    for (int kk = 0; kk < 2; kk++) {
      f16x8 aq = *reinterpret_cast<const f16x8*>(
          &qh16[(size_t)(bhS + ib + mt * 16 + l15) * 64 + kk * 32 + quad * 8]);
      f16x8 ak = *reinterpret_cast<const f16x8*>(
          &kh16[(size_t)(bhS + ib + mt * 16 + l15) * 64 + kk * 32 + quad * 8]);
      #pragma unroll
      for (int nt = 0; nt < 2; nt++) {
        aacc[mt][nt] = __builtin_amdgcn_mfma_f32_16x16x32_f16(aq, qheB[nt][kk], aacc[mt][nt], 0, 0, 0);
        kacc[mt][nt] = __builtin_amdgcn_mfma_f32_16x16x32_f16(ak, kheB[nt][kk], kacc[mt][nt], 0, 0, 0);
      }
      eacc[mt] = __builtin_amdgcn_mfma_f32_16x16x32_f16(aq, qeeB[kk], eacc[mt], 0, 0, 0);
      eacc[mt] = __builtin_amdgcn_mfma_f32_16x16x32_f16(ak, keeB[kk], eacc[mt], 0, 0, 0);
    }
  }

  #pragma unroll
  for (int mt = 0; mt < 2; mt++) {
    #pragma unroll
    for (int r = 0; r < 4; r++) {
      int i = ib + mt * 16 + quad * 4 + r;
      size_t base32 = (size_t)(bhS + i) * 32;
      #pragma unroll
      for (int nt = 0; nt < 2; nt++) {
        Aq[base32 + nt * 16 + l15] = aacc[mt][nt][r];
        Bkh16[base32 + nt * 16 + l15] = f2h(kacc[mt][nt][r]);
      }
      QKe16[(size_t)(bhS + i) * 16 + l15] = f2h(eacc[mt][r]);
    }
  }
}

// ---------------------------------------------------------------------------
// Fused MFMA attention v10 = v9 with f16 Bkh/QKe inputs (from table_mfma).
// Main-loop structure, register binning, barrier-free design unchanged.
// ---------------------------------------------------------------------------
__global__ __launch_bounds__(256, 4) void attn_mfma(
    const unsigned short* __restrict__ qh16, const unsigned short* __restrict__ kh16,
    const unsigned short* __restrict__ vht,
    const float* __restrict__ Aq, const unsigned short* __restrict__ QKe16,
    const unsigned short* __restrict__ Bkh16,
    const float* __restrict__ vhe, const float* __restrict__ vee,
    const unsigned short* __restrict__ de16,
    unsigned short* __restrict__ outp_bf)
{
  const int blk = blockIdx.x;
  const int rt = blk >> 7;             // XCD-affinity: same-bh tiles share XCD
  const int bh = blk & 127;
  const int b = bh >> 3, h = bh & 7;
  const int i0 = rt * 64;
  const int tid = threadIdx.x;
  const int w = tid >> 6;
  const int lane = tid & 63;
  const int l15 = lane & 15, quad = lane >> 4;
  const int bhS = bh * 512;
  const int iL = w * 16 + l15;         // this lane's block-local i-row

  __shared__ union {
    struct {
      float AqF[64][34];               // 8704 B (loop, read-only)
      unsigned short QKes[64][16];     // 2048 B (loop, read-only)
    } a;
    unsigned short embT[64][72];       // 9216 B (epilogue only)
  } U;                                 // 10752 B
  __shared__ unsigned short Pp[4][16][40];    // 5120 B per-wave P tile
  __shared__ unsigned short bkhw[4][32][36];  // 9216 B per-wave Bkh f16 copy
  // total 25,088 B

  // ---- Phase A staging (once per block)
  {
    int r = tid >> 2, c = (tid & 3) * 8;   // AqF: 64x32 f32
    float4 a0 = *reinterpret_cast<const float4*>(&Aq[(bhS + i0 + r)*32 + c]);
    float4 a1 = *reinterpret_cast<const float4*>(&Aq[(bhS + i0 + r)*32 + c + 4]);
    *reinterpret_cast<float2*>(&U.a.AqF[r][c])     = make_float2(a0.x, a0.y);
    *reinterpret_cast<float2*>(&U.a.AqF[r][c + 2]) = make_float2(a0.z, a0.w);
    *reinterpret_cast<float2*>(&U.a.AqF[r][c + 4]) = make_float2(a1.x, a1.y);
    *reinterpret_cast<float2*>(&U.a.AqF[r][c + 6]) = make_float2(a1.z, a1.w);
  }
  {
    int r = tid >> 2, t4 = (tid & 3) * 4;  // QKes: 64x16 f16 copy
    ushort4 v4 = *reinterpret_cast<const ushort4*>(&QKe16[(bhS + i0 + r)*16 + t4]);
    *reinterpret_cast<ushort4*>(&U.a.QKes[r][t4]) = v4;
  }

  // Q as MFMA B-fragment (loop-invariant): lane holds Q[i=iL][d=quad*8..]
  f16x8 bq0 = *reinterpret_cast<const f16x8*>(&qh16[(size_t)(bhS + i0 + iL)*64 + quad*8]);
  f16x8 bq1 = *reinterpret_cast<const f16x8*>(&qh16[(size_t)(bhS + i0 + iL)*64 + 32 + quad*8]);
  __syncthreads();   // the ONLY pre-loop barrier (AqF/QKes ready)

  const size_t deBase = ((size_t)b*512 + i0 + iL) * 512;  // lane's de16 row
  // per-lane Bkh staging coords: lane covers row brow, cols bcol..bcol+15
  const int brow = lane >> 1, bcol = (lane & 1) * 16;

  f32x4 Oacc[4];
  #pragma unroll
  for (int nt = 0; nt < 4; nt++) Oacc[nt] = (f32x4){0.f,0.f,0.f,0.f};
  float sum = 0.f;

  // per-lane register mass bins for row iL (this quad's j-slice)
  float hb[32], eb[16];
  #pragma unroll
  for (int t = 0; t < 32; t++) hb[t] = 0.f;
  #pragma unroll
  for (int t = 0; t < 16; t++) eb[t] = 0.f;

  for (int jc = 0; jc < 16; jc++) {
    const int j0 = jc * 32;

    // per-lane dist/edge (independent global loads; TLP hides latency)
    ushort4 deA = *reinterpret_cast<const ushort4*>(&de16[deBase + j0 + quad*4]);
    ushort4 deB = *reinterpret_cast<const ushort4*>(&de16[deBase + j0 + 16 + quad*4]);

    // stage this chunk's Bkh 32x32 f16 into the wave's own LDS copy;
    // wave-in-order LDS pipe orders these writes before the gathers below.
    {
      const unsigned short* src = &Bkh16[(size_t)(bhS + j0 + brow)*32 + bcol];
      #pragma unroll
      for (int g = 0; g < 4; g++) {
        ushort4 u = *reinterpret_cast<const ushort4*>(&src[g*4]);
        *reinterpret_cast<ushort4*>(&bkhw[w][brow][bcol + g*4]) = u;
      }
    }

    // QK swapped: C[j = quad*4+r (+tile*16), i = l15]; K frags from global
    #pragma unroll
    for (int tile = 0; tile < 2; tile++) {
      const size_t krow = (size_t)(bhS + j0 + tile*16 + l15) * 64;
      f16x8 kf0 = *reinterpret_cast<const f16x8*>(&kh16[krow + quad*8]);
      f16x8 kf1 = *reinterpret_cast<const f16x8*>(&kh16[krow + 32 + quad*8]);
      f32x4 sacc = (f32x4){0.f,0.f,0.f,0.f};
      sacc = __builtin_amdgcn_mfma_f32_16x16x32_f16(kf0, bq0, sacc, 0, 0, 0);
      sacc = __builtin_amdgcn_mfma_f32_16x16x32_f16(kf1, bq1, sacc, 0, 0, 0);
      const int jbase = tile*16 + quad*4;
      const ushort4 de = tile ? deB : deA;
      ushort4 pw;

#define SCALAR_R(rr, ue, pdst)                                                \
      {                                                                       \
        const unsigned u_ = (ue);                                             \
        const int t_ = u_ & 0xFF, e_ = u_ >> 8;                               \
        float bias_ = U.a.AqF[iL][t_] + h2f(bkhw[w][jbase + rr][t_])          \
                    + h2f(U.a.QKes[iL][e_]);                                  \
        float s_ = (sacc[rr] + bias_) * 0.125f;                               \
        float p_ = __expf(fminf(s_, 10.f));                                   \
        sum += p_;                                                            \
        _Pragma("unroll")                                                     \
        for (int t = 0; t < 32; t++) hb[t] += (t == t_) ? p_ : 0.f;           \
        _Pragma("unroll")                                                     \
        for (int t = 0; t < 16; t++) eb[t] += (t == e_) ? p_ : 0.f;           \
        pdst = f2h(p_);                                                       \
      }
      SCALAR_R(0, de.x, pw.x)
      SCALAR_R(1, de.y, pw.y)
      SCALAR_R(2, de.z, pw.z)
      SCALAR_R(3, de.w, pw.w)
#undef SCALAR_R

      // one aligned b64 write: P[i=l15][j = jbase..jbase+3]
      *reinterpret_cast<ushort4*>(&Pp[w][l15][jbase]) = pw;
    }

    // PV via MFMA (K=32 over this chunk); A = P (wave-private), B = V^T global
    {
      f16x8 ap = *reinterpret_cast<const f16x8*>(&Pp[w][l15][quad*8]);
      const size_t vbase = ((size_t)bh*16 + jc)*2048;
      #pragma unroll
      for (int nt = 0; nt < 4; nt++) {
        f16x8 bv = *reinterpret_cast<const f16x8*>(
            &vht[vbase + (nt*16 + l15)*32 + quad*8]);
        Oacc[nt] = __builtin_amdgcn_mfma_f32_16x16x32_f16(ap, bv, Oacc[nt], 0, 0, 0);
      }
    }
    // NO barrier: everything in this loop is wave-private or read-only.
  }

  // cross-quad reduce: combine the 4 quads' j-slices of row iL.
  sum += __shfl_xor(sum, 16);
  sum += __shfl_xor(sum, 32);
  #pragma unroll
  for (int t = 0; t < 32; t++) {
    hb[t] += __shfl_xor(hb[t], 16);
    hb[t] += __shfl_xor(hb[t], 32);
  }
  #pragma unroll
  for (int t = 0; t < 16; t++) {
    eb[t] += __shfl_xor(eb[t], 16);
    eb[t] += __shfl_xor(eb[t], 32);
  }
  float ri[4];
  #pragma unroll
  for (int r = 0; r < 4; r++) ri[r] = 1.0f / __shfl(sum, quad*4 + r);

  __syncthreads();   // all waves done reading U.a before embT overlays it

  // stage embT [d][k]: k<32 -> vhe, 32..47 -> vee, else 0
  {
    int d = tid & 63, ks0 = (tid >> 6) * 16;
    #pragma unroll
    for (int g = 0; g < 4; g++) {
      ushort4 u;
      #pragma unroll
      for (int kk = 0; kk < 4; kk++) {
        int k = ks0 + g*4 + kk;
        float val = (k < 32) ? vhe[k*512 + h*64 + d]
                  : (k < 48) ? vee[(k-32)*512 + h*64 + d] : 0.f;
        ((unsigned short*)&u)[kk] = f2h(val);
      }
      *reinterpret_cast<ushort4*>(&U.embT[d][ks0 + g*4]) = u;
    }
  }
  __syncthreads();   // embT visible to all waves

  // mass . emb via MFMA; A-frags built from register bins (static selects)
  {
    f16x8 am0, am1;
    #pragma unroll
    for (int j = 0; j < 8; j++) {
      float hv = (quad == 0) ? hb[j]
               : (quad == 1) ? hb[8 + j]
               : (quad == 2) ? hb[16 + j] : hb[24 + j];
      am0[j] = (_Float16)hv;
      float ve = (quad == 0) ? eb[j]
               : (quad == 1) ? eb[8 + j] : 0.f;
      am1[j] = (_Float16)ve;
    }
    #pragma unroll
    for (int nt = 0; nt < 4; nt++) {
      f16x8 be0 = *reinterpret_cast<const f16x8*>(&U.embT[nt*16 + l15][quad*8]);
      f16x8 be1 = *reinterpret_cast<const f16x8*>(&U.embT[nt*16 + l15][32 + quad*8]);
      Oacc[nt] = __builtin_amdgcn_mfma_f32_16x16x32_f16(am0, be0, Oacc[nt], 0, 0, 0);
      Oacc[nt] = __builtin_amdgcn_mfma_f32_16x16x32_f16(am1, be1, Oacc[nt], 0, 0, 0);
    }
  }

  // normalize + store bf16
  #pragma unroll
  for (int nt = 0; nt < 4; nt++) {
    #pragma unroll
    for (int r = 0; r < 4; r++) {
      int srow = i0 + w*16 + quad*4 + r;
      outp_bf[(size_t)(b*512 + srow)*512 + h*64 + nt*16 + l15] = f2bf(Oacc[nt][r] * ri[r]);
    }
  }
}

// ---------------------------------------------------------------------------
// Output proj: X = bf16 (attn output), W = f32 Wo converted in staging.
// Register prefetch as in proj_fused.
// ---------------------------------------------------------------------------
__global__ __launch_bounds__(256) void out_mfma(
    const unsigned short* __restrict__ X, const float* __restrict__ Wof,
    const float* __restrict__ bias, float* __restrict__ Y)
{
  __shared__ unsigned short As[128][40];
  __shared__ unsigned short Bs[128][40];
  const int tid = threadIdx.x;
  const int m0 = blockIdx.x * 128;
  const int n0 = blockIdx.y * 128;
  const int lane = tid & 63;
  const int w = tid >> 6;
  const int wr = w >> 1, wc = w & 1;
  const int l15 = lane & 15, quad = lane >> 4;

  const int srow = tid & 127;
  const bool isA = (tid < 128);
  const unsigned short* srcA = &X[(size_t)(m0 + srow) * 512];
  const float* srcB = &Wof[(size_t)(n0 + srow) * 512];
  unsigned short* dstrow = isA ? As[srow] : Bs[srow];

  f32x4 acc[4][4];
  #pragma unroll
  for (int i = 0; i < 4; i++)
    #pragma unroll
    for (int j = 0; j < 4; j++) acc[i][j] = (f32x4){0.f, 0.f, 0.f, 0.f};

  uint4 pa[4]; float4 pb[8];
  if (isA) {
    #pragma unroll
    for (int u = 0; u < 4; u++)
      pa[u] = *reinterpret_cast<const uint4*>(&srcA[u * 8]);
  } else {
    #pragma unroll
    for (int u = 0; u < 8; u++)
      pb[u] = *reinterpret_cast<const float4*>(&srcB[u * 4]);
  }

  for (int k0 = 0; k0 < 512; k0 += 32) {
    __syncthreads();
    if (isA) {
      #pragma unroll
      for (int u = 0; u < 4; u++)
        *reinterpret_cast<uint4*>(&dstrow[u * 8]) = pa[u];
    } else {
      #pragma unroll
      for (int u = 0; u < 4; u++) {
        float4 a = pb[2*u], b2 = pb[2*u + 1];
        ushort4 lo, hi;
        lo.x = f2bf(a.x);  lo.y = f2bf(a.y);  lo.z = f2bf(a.z);  lo.w = f2bf(a.w);
        hi.x = f2bf(b2.x); hi.y = f2bf(b2.y); hi.z = f2bf(b2.z); hi.w = f2bf(b2.w);
        *reinterpret_cast<ushort4*>(&dstrow[u * 8]) = lo;
        *reinterpret_cast<ushort4*>(&dstrow[u * 8 + 4]) = hi;
      }
    }
    __syncthreads();
    if (k0 < 480) {
      if (isA) {
        #pragma unroll
        for (int u = 0; u < 4; u++)
          pa[u] = *reinterpret_cast<const uint4*>(&srcA[k0 + 32 + u * 8]);
      } else {
        #pragma unroll
        for (int u = 0; u < 8; u++)
          pb[u] = *reinterpret_cast<const float4*>(&srcB[k0 + 32 + u * 4]);
      }
    }
    bf16x8 af[4], bfr[4];
    #pragma unroll
    for (int mt = 0; mt < 4; mt++)
      af[mt] = *reinterpret_cast<const bf16x8*>(&As[wr * 64 + mt * 16 + l15][quad * 8]);
    #pragma unroll
    for (int nt = 0; nt < 4; nt++)
      bfr[nt] = *reinterpret_cast<const bf16x8*>(&Bs[wc * 64 + nt * 16 + l15][quad * 8]);
    #pragma unroll
    for (int mt = 0; mt < 4; mt++)
      #pragma unroll
      for (int nt = 0; nt < 4; nt++)
        acc[mt][nt] = __builtin_amdgcn_mfma_f32_16x16x32_bf16(
            af[mt], bfr[nt], acc[mt][nt], 0, 0, 0);
  }

  float bn[4];
  #pragma unroll
  for (int nt = 0; nt < 4; nt++)
    bn[nt] = bias[n0 + wc * 64 + nt * 16 + l15];
  #pragma unroll
  for (int mt = 0; mt < 4; mt++) {
    #pragma unroll
    for (int r = 0; r < 4; r++) {
      int m = m0 + wr * 64 + mt * 16 + quad * 4 + r;
      #pragma unroll
      for (int nt = 0; nt < 4; nt++) {
        int n = n0 + wc * 64 + nt * 16 + l15;
        Y[(size_t)m * 512 + n] = acc[mt][nt][r] + bn[nt];
      }
    }
  }
}

// ---------------------------------------------------------------------------
extern "C" void kernel_launch(void* const* d_in, const int* in_sizes, int n_in,
                              void* d_out, int out_size, void* d_ws, size_t ws_size,
                              hipStream_t stream) {
  (void)in_sizes; (void)n_in; (void)out_size; (void)ws_size;
  const float* q    = (const float*)d_in[0];
  const float* k    = (const float*)d_in[1];
  const float* v    = (const float*)d_in[2];
  const float* qhe  = (const float*)d_in[3];
  const float* qee  = (const float*)d_in[4];
  const float* khe  = (const float*)d_in[5];
  const float* kee  = (const float*)d_in[6];
  const float* vhe  = (const float*)d_in[7];
  const float* vee  = (const float*)d_in[8];
  const int*  dist  = (const int*)d_in[9];
  const int*  edge  = (const int*)d_in[10];
  const float* Wq = (const float*)d_in[11];
  const float* bq = (const float*)d_in[12];
  const float* Wk = (const float*)d_in[13];
  const float* bk = (const float*)d_in[14];
  const float* Wv = (const float*)d_in[15];
  const float* bv = (const float*)d_in[16];
  const float* Wo = (const float*)d_in[17];
  const float* bo = (const float*)d_in[18];

  // ---- workspace layout (bytes) ----
  char* ws = (char*)d_ws;
  unsigned short* qh16  = (unsigned short*)(ws + 0);          // 8,388,608 B
  unsigned short* kh16  = (unsigned short*)(ws + 8388608);    // 8,388,608
  unsigned short* vht   = (unsigned short*)(ws + 16777216);   // 8,388,608
  float* Aq             = (float*)(ws + 25165824);            // 8,388,608
  unsigned short* Bkh16 = (unsigned short*)(ws + 33554432);   // 4,194,304 used (slot 8 MB)
  unsigned short* QKe16 = (unsigned short*)(ws + 41943040);   // 2,097,152 used (slot 4 MB)
  unsigned short* de16  = (unsigned short*)(ws + 46137344);   // 8,388,608 packed dist|edge
  unsigned short* outp_bf = (unsigned short*)(ws + 71303168); // 8,388,608

  dim3 blk(256);
  hipLaunchKernelGGL(pack_de, dim3(2048), blk, 0, stream, dist, edge, de16);
  hipLaunchKernelGGL(proj_fused, dim3(64, 4, 3), blk, 0, stream,
                     q, k, v, Wq, Wk, Wv, bq, bk, bv, qh16, kh16, vht);
  hipLaunchKernelGGL(table_mfma, dim3(512), blk, 0, stream,
                     qh16, kh16, qhe, qee, khe, kee, Aq, QKe16, Bkh16);
  hipLaunchKernelGGL(attn_mfma, dim3(1024), blk, 0, stream,
                     qh16, kh16, vht, Aq, QKe16, Bkh16, vhe, vee, de16, outp_bf);
  hipLaunchKernelGGL(out_mfma, dim3(64, 4), blk, 0, stream,
                     outp_bf, Wo, bo, (float*)d_out);
}